// Round 6
// baseline (57.902 us; speedup 1.0000x reference)
//
#include <hip/hip_runtime.h>

// SpikeLoss: loss = 0.5 * sum((outputs - psp(target))^2)
// psp_t = (1/tau) * sum_{s<=t} d^{t-s} x_s, d = 1-1/tau  (T=32, last axis).
// Lane owns 4 consecutive t (one float4); 8 lanes per row. Fully coalesced.
//
// R5 post-mortem: body identical to R2 yet +8us (57.8 vs 49.5). R3 (57.2) and
// R5 (57.8) share only {hipMemsetAsync node + atomic ending} -> structural.
// Suspect: SDMA memset node (cross-engine sync before compute node).
// R6 A/B: ONLY change vs R5 = zero d_out via a 1-thread KERNEL node (compute
// queue, no SDMA) instead of hipMemsetAsync. If still ~57us, the atomic tail
// is the cost -> revert to R2 two-kernel and declare roofline.

#define NBLOCKS 2048
#define NTHREADS 256

__global__ void zero_out(float* __restrict__ out) { out[0] = 0.0f; }

__device__ __forceinline__ float process_one(
    float4 x, float4 o, int j,
    float d, float d2, float d3, float d4, float d8, float d16, float inv_tau)
{
    // local inclusive scan over 4 time steps
    float s0 = x.x;
    float s1 = s0 * d + x.y;
    float s2 = s1 * d + x.z;
    float s3 = s2 * d + x.w;

    // weighted Kogge-Stone inclusive scan of segment totals across 8 lanes
    float S = s3;
    float u;
    u = __shfl_up(S, 1, 8); S += (j >= 1) ? d4  * u : 0.0f;
    u = __shfl_up(S, 2, 8); S += (j >= 2) ? d8  * u : 0.0f;
    u = __shfl_up(S, 4, 8); S += (j >= 4) ? d16 * u : 0.0f;

    // carry-in from previous lanes: contribution at local k is d^{k+1} * S_{j-1}
    float cp = __shfl_up(S, 1, 8);
    cp = (j >= 1) ? cp : 0.0f;
    s0 += cp * d;
    s1 += cp * d2;
    s2 += cp * d3;
    s3 += cp * d4;

    float e0 = o.x - s0 * inv_tau;
    float e1 = o.y - s1 * inv_tau;
    float e2 = o.z - s2 * inv_tau;
    float e3 = o.w - s3 * inv_tau;
    return e0 * e0 + e1 * e1 + e2 * e2 + e3 * e3;
}

__global__ __launch_bounds__(NTHREADS) void spike_loss_fused(
    const float* __restrict__ outputs,
    const float* __restrict__ target,
    const int* __restrict__ tau_p,
    float* __restrict__ out,
    int total4)
{
    const float tau = (float)tau_p[0];
    const float d  = 1.0f - 1.0f / tau;   // 0.75 for tau=4 (exact)
    const float inv_tau = 1.0f / tau;
    const float d2 = d * d;
    const float d3 = d2 * d;
    const float d4 = d2 * d2;
    const float d8 = d4 * d4;
    const float d16 = d8 * d8;

    const int lane = threadIdx.x & 63;
    const int j = lane & 7;               // position within 8-lane row segment

    const float4* __restrict__ t4 = (const float4*)target;
    const float4* __restrict__ o4 = (const float4*)outputs;

    float acc = 0.0f;
    const int stride = gridDim.x * blockDim.x;
    int g = blockIdx.x * blockDim.x + threadIdx.x;

    // main loop: 4 float4-pairs in flight before dependent math (R2 structure)
    for (; g + 3 * stride < total4; g += 4 * stride) {
        float4 x0 = t4[g];
        float4 x1 = t4[g + stride];
        float4 x2 = t4[g + 2 * stride];
        float4 x3 = t4[g + 3 * stride];
        float4 o0 = o4[g];
        float4 o1 = o4[g + stride];
        float4 o2 = o4[g + 2 * stride];
        float4 o3 = o4[g + 3 * stride];

        acc += process_one(x0, o0, j, d, d2, d3, d4, d8, d16, inv_tau);
        acc += process_one(x1, o1, j, d, d2, d3, d4, d8, d16, inv_tau);
        acc += process_one(x2, o2, j, d, d2, d3, d4, d8, d16, inv_tau);
        acc += process_one(x3, o3, j, d, d2, d3, d4, d8, d16, inv_tau);
    }
    // tail (not taken for the bench shape; segments stay convergent since
    // stride and total4 are multiples of 8)
    for (; g < total4; g += stride) {
        acc += process_one(t4[g], o4[g], j, d, d2, d3, d4, d8, d16, inv_tau);
    }

    // wave reduce (64 lanes)
    #pragma unroll
    for (int o = 32; o > 0; o >>= 1) acc += __shfl_down(acc, o, 64);

    __shared__ float wsum[NTHREADS / 64];
    if (lane == 0) wsum[threadIdx.x >> 6] = acc;
    __syncthreads();
    if (threadIdx.x == 0) {
        float s = 0.0f;
        #pragma unroll
        for (int w = 0; w < NTHREADS / 64; ++w) s += wsum[w];
        atomicAdd(out, 0.5f * s);   // coherent by itself; no fence needed
    }
}

extern "C" void kernel_launch(void* const* d_in, const int* in_sizes, int n_in,
                              void* d_out, int out_size, void* d_ws, size_t ws_size,
                              hipStream_t stream) {
    const float* outputs = (const float*)d_in[0];
    const float* target  = (const float*)d_in[1];
    // d_in[2] = n_steps (T=32 baked into the 8-lane-per-row layout)
    const int*   tau_p   = (const int*)d_in[3];

    const int total4 = in_sizes[0] / 4;

    zero_out<<<1, 1, 0, stream>>>((float*)d_out);      // compute-queue zeroing node (no SDMA)
    spike_loss_fused<<<NBLOCKS, NTHREADS, 0, stream>>>(
        outputs, target, tau_p, (float*)d_out, total4);
}

// Round 7
// 49.127 us; speedup vs baseline: 1.1786x; 1.1786x over previous
//
#include <hip/hip_runtime.h>

// SpikeLoss: loss = 0.5 * sum((outputs - psp(target))^2)
// psp_t = (1/tau) * sum_{s<=t} d^{t-s} x_s, d = 1-1/tau  (T=32, last axis).
// Lane owns 4 consecutive t (one float4); 8 lanes per row. Fully coalesced.
//
// R6 post-mortem: fused atomics cost ~8us (2048 same-address fp32 atomics
// serialize at drain) regardless of zero-node engine; and any atomic scheme
// needs the zero node (no re-poison between replays). Two-kernel structure
// (R2, 49.5us) is structurally optimal.
// R7: R2 structure + depth-3 DS chain: carry cp_j = S3_{j-1} = S2_{j-1} +
// d^16*S2_{j-5}, so the two carry shuffles issue in parallel after KS level 2
// (was 3 serial KS levels + 1 serial carry shfl = 4 waits; now 3).

#define NBLOCKS 2048
#define NTHREADS 256

__device__ __forceinline__ float process_one(
    float4 x, float4 o, int j,
    float d, float d2, float d3, float d4, float d8, float d16, float inv_tau)
{
    // local inclusive scan over 4 time steps
    float s0 = x.x;
    float s1 = s0 * d + x.y;
    float s2 = s1 * d + x.z;
    float s3 = s2 * d + x.w;

    // KS levels 1,2 on segment totals (8-lane segment = one row of T=32)
    float S = s3;
    float u;
    u = __shfl_up(S, 1, 8); S += (j >= 1) ? d4 * u : 0.0f;
    u = __shfl_up(S, 2, 8); S += (j >= 2) ? d8 * u : 0.0f;   // S == S2_j

    // carry-in cp_j = S3_{j-1} = S2_{j-1} + d^16 * S2_{j-5}
    // (two independent shuffles -> one lgkmcnt wait; S3 never materialized)
    float u1 = __shfl_up(S, 1, 8);
    float u5 = __shfl_up(S, 5, 8);
    float cp = ((j >= 1) ? u1 : 0.0f) + ((j >= 5) ? d16 * u5 : 0.0f);

    s0 += cp * d;
    s1 += cp * d2;
    s2 += cp * d3;
    s3 += cp * d4;

    float e0 = o.x - s0 * inv_tau;
    float e1 = o.y - s1 * inv_tau;
    float e2 = o.z - s2 * inv_tau;
    float e3 = o.w - s3 * inv_tau;
    return e0 * e0 + e1 * e1 + e2 * e2 + e3 * e3;
}

__global__ __launch_bounds__(NTHREADS) void spike_loss_main(
    const float* __restrict__ outputs,
    const float* __restrict__ target,
    const int* __restrict__ tau_p,
    float* __restrict__ partials,
    int total4)
{
    const float tau = (float)tau_p[0];
    const float d  = 1.0f - 1.0f / tau;   // 0.75 for tau=4 (exact)
    const float inv_tau = 1.0f / tau;
    const float d2 = d * d;
    const float d3 = d2 * d;
    const float d4 = d2 * d2;
    const float d8 = d4 * d4;
    const float d16 = d8 * d8;

    const int lane = threadIdx.x & 63;
    const int j = lane & 7;               // position within 8-lane row segment

    const float4* __restrict__ t4 = (const float4*)target;
    const float4* __restrict__ o4 = (const float4*)outputs;

    float acc = 0.0f;
    const int stride = gridDim.x * blockDim.x;
    int g = blockIdx.x * blockDim.x + threadIdx.x;

    // main loop: 4 float4-pairs in flight before dependent math (R2 structure)
    for (; g + 3 * stride < total4; g += 4 * stride) {
        float4 x0 = t4[g];
        float4 x1 = t4[g + stride];
        float4 x2 = t4[g + 2 * stride];
        float4 x3 = t4[g + 3 * stride];
        float4 o0 = o4[g];
        float4 o1 = o4[g + stride];
        float4 o2 = o4[g + 2 * stride];
        float4 o3 = o4[g + 3 * stride];

        acc += process_one(x0, o0, j, d, d2, d3, d4, d8, d16, inv_tau);
        acc += process_one(x1, o1, j, d, d2, d3, d4, d8, d16, inv_tau);
        acc += process_one(x2, o2, j, d, d2, d3, d4, d8, d16, inv_tau);
        acc += process_one(x3, o3, j, d, d2, d3, d4, d8, d16, inv_tau);
    }
    // tail (not taken for the bench shape; segments stay convergent since
    // stride and total4 are multiples of 8)
    for (; g < total4; g += stride) {
        acc += process_one(t4[g], o4[g], j, d, d2, d3, d4, d8, d16, inv_tau);
    }

    // wave reduce (64 lanes)
    #pragma unroll
    for (int o = 32; o > 0; o >>= 1) acc += __shfl_down(acc, o, 64);

    __shared__ float wsum[NTHREADS / 64];
    if (lane == 0) wsum[threadIdx.x >> 6] = acc;
    __syncthreads();
    if (threadIdx.x == 0) {
        float s = 0.0f;
        #pragma unroll
        for (int w = 0; w < NTHREADS / 64; ++w) s += wsum[w];
        partials[blockIdx.x] = s;
    }
}

__global__ __launch_bounds__(NTHREADS) void spike_loss_final(
    const float* __restrict__ partials, float* __restrict__ out, int n)
{
    float acc = 0.0f;
    for (int i = threadIdx.x; i < n; i += NTHREADS) acc += partials[i];
    #pragma unroll
    for (int o = 32; o > 0; o >>= 1) acc += __shfl_down(acc, o, 64);

    __shared__ float wsum[NTHREADS / 64];
    const int lane = threadIdx.x & 63;
    if (lane == 0) wsum[threadIdx.x >> 6] = acc;
    __syncthreads();
    if (threadIdx.x == 0) {
        float s = 0.0f;
        #pragma unroll
        for (int w = 0; w < NTHREADS / 64; ++w) s += wsum[w];
        out[0] = 0.5f * s;
    }
}

extern "C" void kernel_launch(void* const* d_in, const int* in_sizes, int n_in,
                              void* d_out, int out_size, void* d_ws, size_t ws_size,
                              hipStream_t stream) {
    const float* outputs = (const float*)d_in[0];
    const float* target  = (const float*)d_in[1];
    // d_in[2] = n_steps (T=32 baked into the 8-lane-per-row layout)
    const int*   tau_p   = (const int*)d_in[3];

    float* partials = (float*)d_ws;   // NBLOCKS floats, fully overwritten each call
    const int total4 = in_sizes[0] / 4;

    spike_loss_main<<<NBLOCKS, NTHREADS, 0, stream>>>(outputs, target, tau_p, partials, total4);
    spike_loss_final<<<1, NTHREADS, 0, stream>>>(partials, (float*)d_out, NBLOCKS);
}